// Round 7
// baseline (98.065 us; speedup 1.0000x reference)
//
#include <hip/hip_runtime.h>

// Overlapped-chunk HMM forward filter, all-VALU, zero mid-chain loads.
// CHUNK_L=32, WARMUP_W=16 -> 15625 chunks, ~3.8 waves/SIMD.
// Carried UNNORMALIZED filtrate (R6 structure): serial chain = dot16 -> *g.
// R7: (1) whole 48-float y window preloaded to VGPRs, loops fully unrolled ->
// no memory dependency inside the chain; (2) preamble de-LDS'ed: softmax via
// DPP ring reductions, stationary pi via 48 all-VALU power iterations (no
// matrix squaring, no ds_bpermute chains, single barrier for the P transpose).
#define CHUNK_L 32
#define WARMUP_W 16
#define PI_ITERS 48

typedef float v2f __attribute__((ext_vector_type(2)));

template<int K> __device__ __forceinline__ float bcast16(float v) {
    // broadcast lane (row_start + K) across the 16-lane row (row_newbcast)
    return __int_as_float(__builtin_amdgcn_update_dpp(
        0, __float_as_int(v), 0x150 | K, 0xF, 0xF, true));
}
template<int N> __device__ __forceinline__ float rowror16(float v) {
    return __int_as_float(__builtin_amdgcn_update_dpp(
        0, __float_as_int(v), 0x120 | N, 0xF, 0xF, true));
}
__device__ __forceinline__ float rowsum16(float p) {
    p += rowror16<1>(p);
    p += rowror16<2>(p);
    p += rowror16<4>(p);
    p += rowror16<8>(p);
    return p;
}
__device__ __forceinline__ float rowmax16(float p) {
    p = fmaxf(p, rowror16<1>(p));
    p = fmaxf(p, rowror16<2>(p));
    p = fmaxf(p, rowror16<4>(p));
    p = fmaxf(p, rowror16<8>(p));
    return p;
}

// (a @ P)_j : 16 DPP broadcasts + 8 v_pk_fma_f32 (2 indep accumulator pairs)
__device__ __forceinline__ float dot16(float a, const v2f* pc2) {
    v2f b0, b1, u01, u23;
    b0.x = bcast16<0>(a);  b0.y = bcast16<1>(a);
    b1.x = bcast16<2>(a);  b1.y = bcast16<3>(a);
    u01 = b0 * pc2[0];
    u23 = b1 * pc2[1];
    b0.x = bcast16<4>(a);  b0.y = bcast16<5>(a);
    b1.x = bcast16<6>(a);  b1.y = bcast16<7>(a);
    u01 = b0 * pc2[2] + u01;
    u23 = b1 * pc2[3] + u23;
    b0.x = bcast16<8>(a);  b0.y = bcast16<9>(a);
    b1.x = bcast16<10>(a); b1.y = bcast16<11>(a);
    u01 = b0 * pc2[4] + u01;
    u23 = b1 * pc2[5] + u23;
    b0.x = bcast16<12>(a); b0.y = bcast16<13>(a);
    b1.x = bcast16<14>(a); b1.y = bcast16<15>(a);
    u01 = b0 * pc2[6] + u01;
    u23 = b1 * pc2[7] + u23;
    v2f u = u01 + u23;
    return u.x + u.y;
}

__global__ __launch_bounds__(256, 4) void hmm_filter_kernel(
    const float* __restrict__ y,
    const float* __restrict__ logits,
    const float* __restrict__ mu,
    const float* __restrict__ log_sigma,
    float* __restrict__ out,
    int T, int nchunks)
{
    __shared__ float Plds[256];

    const int tid = (int)threadIdx.x;
    const int j   = tid & 15;     // state / column index
    const int g   = tid >> 4;     // row (softmax) / group id (main)

    // ---- P = softmax(logits, axis=-1), all-DPP reductions ----
    const float l  = logits[tid];
    const float mx = rowmax16(l);
    const float e  = __builtin_amdgcn_exp2f((l - mx) * 1.4426950408889634f);
    const float Pv = e * __builtin_amdgcn_rcpf(rowsum16(e));
    Plds[tid] = Pv;
    __syncthreads();              // the ONLY barrier

    // P column j as 8 float2 pairs (k ascending): needs cross-row -> via LDS
    v2f pc2[8];
    #pragma unroll
    for (int k = 0; k < 8; ++k) {
        pc2[k].x = Plds[(2 * k)     * 16 + j];
        pc2[k].y = Plds[(2 * k + 1) * 16 + j];
    }

    const int chunk = (int)blockIdx.x * 16 + g;
    if (chunk >= nchunks) return;           // after the barrier: safe

    // ---- stationary pi via power iteration (all-VALU, no LDS/barriers) ----
    float api = 0.0625f;
    #pragma unroll
    for (int i = 0; i < PI_ITERS; ++i) api = dot16(api, pc2);
    api *= __builtin_amdgcn_rcpf(rowsum16(api));

    // emission constants for state j
    const float isj = __expf(-log_sigma[j]);              // 1/sigma_j
    const float nmj = -mu[j] * isj;                       // z = fma(y, isj, nmj)
    const float lcf = __log2f(0.3989422804014327f * isj); // log2(coef)
    const float K2  = -0.7213475204444817f;               // -0.5*log2(e)
    auto emis = [&](float yt) -> float {
        float z = fmaf(yt, isj, nmj);
        return __builtin_amdgcn_exp2f(fmaf(z * z, K2, lcf));
    };

    const int wfrom = chunk * CHUNK_L;
    int t0 = wfrom - WARMUP_W; if (t0 < 0) t0 = 0;   // chunk 0 only
    const bool first = (wfrom == 0);

    // ---- preload the chain's entire y window: 48 floats, aligned ----
    const float4* yb = (const float4*)(y + t0);
    float4 Y[12];
    #pragma unroll
    for (int i = 0; i < 12; ++i) Y[i] = yb[i];

    // ---- warm-up: 16 unnormalized steps (chunk 0: computed but discarded) ----
    float p = api;
    #pragma unroll
    for (int i = 0; i < 4; ++i) {
        const float4 c4 = Y[i];
        p = dot16(p, pc2) * emis(c4.x);
        p = dot16(p, pc2) * emis(c4.y);
        p = dot16(p, pc2) * emis(c4.z);
        p = dot16(p, pc2) * emis(c4.w);
        if (i == 1) p *= __builtin_amdgcn_rcpf(rowsum16(p));  // underflow guard
    }
    p *= __builtin_amdgcn_rcpf(rowsum16(p));
    if (first) p = api;                    // chunk 0 starts EXACTLY from pi

    // main window registers (chunk 0: Y[0..7], else Y[4..11])
    float4 M[8];
    #pragma unroll
    for (int i = 0; i < 8; ++i) M[i] = first ? Y[i] : Y[i + 4];

    // ---- main chunk: 8 blocks x 4 steps, carried-product normalization ----
    //   q = p@P (= s_prev*ut), pg = q*g (carried), s = rowsum(pg) (= s_prev*ft)
    //   ut = q*r_prev, ft = s*r_prev, utt = pg*rcp(s); renorm via carrying utt3
    float* __restrict__ pU = out + (wfrom << 4) + j;   // ut
    float* __restrict__ pN = pU + (T << 4);            // u_norm
    float* __restrict__ pF = out + (T << 5) + wfrom;   // ft (lane j==0)

    #pragma unroll
    for (int b = 0; b < 8; ++b) {
        const float4 c4 = M[b];
        const float g0 = emis(c4.x), g1 = emis(c4.y);
        const float g2 = emis(c4.z), g3 = emis(c4.w);

        const float q0  = dot16(p, pc2);
        const float pg0 = q0 * g0;
        const float s0  = rowsum16(pg0);
        const float r0  = __builtin_amdgcn_rcpf(s0);
        const float q1  = dot16(pg0, pc2);
        const float pg1 = q1 * g1;
        const float s1  = rowsum16(pg1);
        const float r1  = __builtin_amdgcn_rcpf(s1);
        const float q2  = dot16(pg1, pc2);
        const float pg2 = q2 * g2;
        const float s2  = rowsum16(pg2);
        const float r2  = __builtin_amdgcn_rcpf(s2);
        const float q3  = dot16(pg2, pc2);
        const float pg3 = q3 * g3;
        const float s3  = rowsum16(pg3);
        const float r3  = __builtin_amdgcn_rcpf(s3);

        const int o = b * 64;
        pU[o]      = q0;
        pU[o + 16] = q1 * r0;
        pU[o + 32] = q2 * r1;
        pU[o + 48] = q3 * r2;
        pN[o]      = pg0 * r0;
        pN[o + 16] = pg1 * r1;
        pN[o + 32] = pg2 * r2;
        const float utt3 = pg3 * r3;
        pN[o + 48] = utt3;
        if (j == 0)
            *(float4*)(pF + b * 4) = make_float4(s0, s1 * r0, s2 * r1, s3 * r2);

        p = utt3;                          // renormalized carry
    }
}

extern "C" void kernel_launch(void* const* d_in, const int* in_sizes, int n_in,
                              void* d_out, int out_size, void* d_ws, size_t ws_size,
                              hipStream_t stream) {
    const float* y      = (const float*)d_in[0];
    const float* logits = (const float*)d_in[1];
    const float* mu     = (const float*)d_in[2];
    const float* ls     = (const float*)d_in[3];
    float* out = (float*)d_out;
    const int T = in_sizes[0];             // 500000 = 32 * 15625 (exact)

    const int nchunks = (T + CHUNK_L - 1) / CHUNK_L;
    const int blocks  = (nchunks + 15) / 16;
    hmm_filter_kernel<<<blocks, 256, 0, stream>>>(y, logits, mu, ls, out,
                                                  T, nchunks);
}

// Round 8
// 96.317 us; speedup vs baseline: 1.0181x; 1.0181x over previous
//
#include <hip/hip_runtime.h>

// Overlapped-chunk HMM forward filter, two-kernel version.
// Setup kernel (1 block): P = softmax(logits), P^T and stationary pi -> d_ws.
// Main kernel: CHUNK_L=16, WARMUP_W=16 -> 31250 chunks, 7813 waves,
// ~7.6 waves/SIMD (R5 measured 61% VALUBusy at this occupancy vs ~25% at 3.8).
// R6's carried-product step: serial chain = dot16 -> *g; rowsum/rcp/outputs
// hang off the chain. launch_bounds(256,8) caps VGPR<=64 for full residency.
#define CHUNK_L 16
#define WARMUP_W 16
#define PI_ITERS 48

typedef float v2f __attribute__((ext_vector_type(2)));

template<int K> __device__ __forceinline__ float bcast16(float v) {
    // broadcast lane (row_start + K) across the 16-lane row (row_newbcast)
    return __int_as_float(__builtin_amdgcn_update_dpp(
        0, __float_as_int(v), 0x150 | K, 0xF, 0xF, true));
}
template<int N> __device__ __forceinline__ float rowror16(float v) {
    return __int_as_float(__builtin_amdgcn_update_dpp(
        0, __float_as_int(v), 0x120 | N, 0xF, 0xF, true));
}
__device__ __forceinline__ float rowsum16(float p) {
    p += rowror16<1>(p);
    p += rowror16<2>(p);
    p += rowror16<4>(p);
    p += rowror16<8>(p);
    return p;
}
__device__ __forceinline__ float rowmax16(float p) {
    p = fmaxf(p, rowror16<1>(p));
    p = fmaxf(p, rowror16<2>(p));
    p = fmaxf(p, rowror16<4>(p));
    p = fmaxf(p, rowror16<8>(p));
    return p;
}

// (a @ P)_j : 16 DPP broadcasts + 8 v_pk_fma_f32 (2 indep accumulator pairs)
__device__ __forceinline__ float dot16(float a, const v2f* pc2) {
    v2f b0, b1, u01, u23;
    b0.x = bcast16<0>(a);  b0.y = bcast16<1>(a);
    b1.x = bcast16<2>(a);  b1.y = bcast16<3>(a);
    u01 = b0 * pc2[0];
    u23 = b1 * pc2[1];
    b0.x = bcast16<4>(a);  b0.y = bcast16<5>(a);
    b1.x = bcast16<6>(a);  b1.y = bcast16<7>(a);
    u01 = b0 * pc2[2] + u01;
    u23 = b1 * pc2[3] + u23;
    b0.x = bcast16<8>(a);  b0.y = bcast16<9>(a);
    b1.x = bcast16<10>(a); b1.y = bcast16<11>(a);
    u01 = b0 * pc2[4] + u01;
    u23 = b1 * pc2[5] + u23;
    b0.x = bcast16<12>(a); b0.y = bcast16<13>(a);
    b1.x = bcast16<14>(a); b1.y = bcast16<15>(a);
    u01 = b0 * pc2[6] + u01;
    u23 = b1 * pc2[7] + u23;
    v2f u = u01 + u23;
    return u.x + u.y;
}

// ---- setup: one block. ws[0..255] = P^T (col-major P), ws[256..271] = pi ----
__global__ __launch_bounds__(256) void hmm_setup_kernel(
    const float* __restrict__ logits, float* __restrict__ ws)
{
    __shared__ float Plds[256];
    const int tid = (int)threadIdx.x;
    const int j   = tid & 15;   // col
    const int g   = tid >> 4;   // row

    const float l  = logits[tid];
    const float mx = rowmax16(l);
    const float e  = __builtin_amdgcn_exp2f((l - mx) * 1.4426950408889634f);
    const float Pv = e * __builtin_amdgcn_rcpf(rowsum16(e));  // P[g][j]
    ws[j * 16 + g] = Pv;                                      // P^T
    Plds[tid] = Pv;
    __syncthreads();

    v2f pc2[8];
    #pragma unroll
    for (int k = 0; k < 8; ++k) {
        pc2[k].x = Plds[(2 * k)     * 16 + j];
        pc2[k].y = Plds[(2 * k + 1) * 16 + j];
    }
    float api = 0.0625f;
    #pragma unroll
    for (int i = 0; i < PI_ITERS; ++i) api = dot16(api, pc2);
    api *= __builtin_amdgcn_rcpf(rowsum16(api));
    if (g == 0) ws[256 + j] = api;
}

// ---- main filter ----
__global__ __launch_bounds__(256, 8) void hmm_filter_kernel(
    const float* __restrict__ y,
    const float* __restrict__ mu,
    const float* __restrict__ log_sigma,
    const float* __restrict__ ws,
    float* __restrict__ out,
    int T, int nchunks)
{
    const int tid = (int)threadIdx.x;
    const int j   = tid & 15;     // state index
    const int g   = tid >> 4;     // group id

    const int chunk = (int)blockIdx.x * 16 + g;
    if (chunk >= nchunks) return;           // no barriers anywhere: safe

    // P column j (contiguous in ws) + pi_j
    v2f pc2[8];
    const float4* colp = (const float4*)(ws + j * 16);
    {
        const float4 A = colp[0], B = colp[1], C = colp[2], D = colp[3];
        pc2[0].x = A.x; pc2[0].y = A.y;  pc2[1].x = A.z; pc2[1].y = A.w;
        pc2[2].x = B.x; pc2[2].y = B.y;  pc2[3].x = B.z; pc2[3].y = B.w;
        pc2[4].x = C.x; pc2[4].y = C.y;  pc2[5].x = C.z; pc2[5].y = C.w;
        pc2[6].x = D.x; pc2[6].y = D.y;  pc2[7].x = D.z; pc2[7].y = D.w;
    }
    const float api = ws[256 + j];

    // emission constants for state j
    const float isj = __expf(-log_sigma[j]);              // 1/sigma_j
    const float nmj = -mu[j] * isj;                       // z = fma(y, isj, nmj)
    const float lcf = __log2f(0.3989422804014327f * isj); // log2(coef)
    const float K2  = -0.7213475204444817f;               // -0.5*log2(e)
    auto emis = [&](float yt) -> float {
        float z = fmaf(yt, isj, nmj);
        return __builtin_amdgcn_exp2f(fmaf(z * z, K2, lcf));
    };

    const int wfrom = chunk * CHUNK_L;
    int t0 = wfrom - WARMUP_W; if (t0 < 0) t0 = 0;   // chunk 0: exact from t=0
    const int Tm4 = T - 4;

    // ---- y pipeline: two 4-blocks in flight ----
    int t = t0;
    float4 c4 = *(const float4*)(y + t);
    float4 n1 = *(const float4*)(y + t + 4);         // t0+4 <= wfrom+4 <= T-12

    float p = api;

    // ---- warm-up: 16 unnormalized steps (chunk 0 skips; lanes masked) ----
    if (t0 < wfrom) {
        #pragma unroll
        for (int b = 0; b < 4; ++b) {
            const float4 n2 = *(const float4*)(y + t + 8);  // <= wfrom+4: in bounds
            p = dot16(p, pc2) * emis(c4.x);
            p = dot16(p, pc2) * emis(c4.y);
            p = dot16(p, pc2) * emis(c4.z);
            p = dot16(p, pc2) * emis(c4.w);
            if (b == 1) p *= __builtin_amdgcn_rcpf(rowsum16(p));  // range guard
            c4 = n1; n1 = n2; t += 4;
        }
    }
    p *= __builtin_amdgcn_rcpf(rowsum16(p));   // enter main with scale 1

    // ---- main chunk: 4 blocks x 4 steps, carried-product normalization ----
    //   q = p@P (= s_prev*ut), pg = q*g (carried), s = rowsum(pg) (= s_prev*ft)
    //   ut = q*r_prev, ft = s*r_prev, utt = pg*rcp(s); renorm by carrying utt3
    float* __restrict__ pU = out + (wfrom << 4) + j;   // ut
    float* __restrict__ pN = pU + (T << 4);            // u_norm
    float* __restrict__ pF = out + (T << 5) + wfrom;   // ft (lane j==0)

    #pragma unroll
    for (int b = 0; b < 4; ++b) {
        int p2 = t + 8; if (p2 > Tm4) p2 = Tm4;        // last chunk clamps
        const float4 n2 = *(const float4*)(y + p2);

        const float g0 = emis(c4.x), g1 = emis(c4.y);
        const float g2 = emis(c4.z), g3 = emis(c4.w);

        const float q0  = dot16(p, pc2);
        const float pg0 = q0 * g0;
        const float s0  = rowsum16(pg0);
        const float r0  = __builtin_amdgcn_rcpf(s0);
        const float q1  = dot16(pg0, pc2);
        const float pg1 = q1 * g1;
        const float s1  = rowsum16(pg1);
        const float r1  = __builtin_amdgcn_rcpf(s1);
        const float q2  = dot16(pg1, pc2);
        const float pg2 = q2 * g2;
        const float s2  = rowsum16(pg2);
        const float r2  = __builtin_amdgcn_rcpf(s2);
        const float q3  = dot16(pg2, pc2);
        const float pg3 = q3 * g3;
        const float s3  = rowsum16(pg3);
        const float r3  = __builtin_amdgcn_rcpf(s3);

        const int o = b * 64;
        pU[o]      = q0;
        pU[o + 16] = q1 * r0;
        pU[o + 32] = q2 * r1;
        pU[o + 48] = q3 * r2;
        pN[o]      = pg0 * r0;
        pN[o + 16] = pg1 * r1;
        pN[o + 32] = pg2 * r2;
        const float utt3 = pg3 * r3;
        pN[o + 48] = utt3;
        if (j == 0)
            *(float4*)(pF + b * 4) = make_float4(s0, s1 * r0, s2 * r1, s3 * r2);

        p = utt3;                          // renormalized carry
        c4 = n1; n1 = n2; t += 4;
    }
}

extern "C" void kernel_launch(void* const* d_in, const int* in_sizes, int n_in,
                              void* d_out, int out_size, void* d_ws, size_t ws_size,
                              hipStream_t stream) {
    const float* y      = (const float*)d_in[0];
    const float* logits = (const float*)d_in[1];
    const float* mu     = (const float*)d_in[2];
    const float* ls     = (const float*)d_in[3];
    float* out = (float*)d_out;
    float* ws  = (float*)d_ws;
    const int T = in_sizes[0];             // 500000 = 16 * 31250 (exact)

    hmm_setup_kernel<<<1, 256, 0, stream>>>(logits, ws);

    const int nchunks = (T + CHUNK_L - 1) / CHUNK_L;
    const int blocks  = (nchunks + 15) / 16;
    hmm_filter_kernel<<<blocks, 256, 0, stream>>>(y, mu, ls, ws, out,
                                                  T, nchunks);
}